// Round 3
// baseline (188.040 us; speedup 1.0000x reference)
//
#include <hip/hip_runtime.h>
#include <hip/hip_bf16.h>
#include <hip/hip_cooperative_groups.h>

namespace cg = cooperative_groups;

// Sizes fixed by setup_inputs()
#define N_EL   1024
#define N_UP   512
#define NNUC   256
#define DIM    256
#define EDIM   32

#define GAIN_F      1.7872135f          // 1/std(silu(N(0,1))), analytic
#define INV_SQRT2_F 0.7071067811865476f

typedef __attribute__((ext_vector_type(8))) short bf16x8;
typedef __attribute__((ext_vector_type(4))) short bf16x4;
typedef __attribute__((ext_vector_type(4))) float f32x4;

__device__ __forceinline__ short f2bf(float x) {
    // Let the compiler emit v_cvt_f32->bf16 and fuse pairs into v_cvt_pk_bf16_f32.
    union { __hip_bfloat16 h; short s; } u;
    u.h = __float2bfloat16(x);
    return u.s;
}

// ---------------------------------------------------------------------------
// One cooperative kernel, 4 phases separated by grid.sync():
//  P0 prep : layout rearrangement + f32->bf16 (tabs, W_edge, W1, W2, elec)
//  P1 edge : fused edge-GEMM * spin-table * k-reduction -> agg (in d_out)
//  P2 gemm1: h = act((elec@W1 + b1 + agg*norm)*scale2) -> hb (bf16)
//  P3 gemm2: out = (elec + act(h@W2 + b2)) * inv_sqrt2 -> d_out
// 256 blocks x 256 threads = 1 block/CU (cooperative co-residency).
// ---------------------------------------------------------------------------
__global__ __launch_bounds__(256) void fused_kernel(
    const float* __restrict__ elec,
    const float* __restrict__ up, const float* __restrict__ dn,
    const float* __restrict__ eemb,
    const float* __restrict__ norm,
    const float* __restrict__ W1, const float* __restrict__ b1,
    const float* __restrict__ Wedge,
    const float* __restrict__ W2, const float* __restrict__ b2,
    const float* __restrict__ s1p, const float* __restrict__ s2p,
    float* __restrict__ tab_up, float* __restrict__ tab_dn,
    short* __restrict__ wedge_arr,
    short* __restrict__ w1f, short* __restrict__ w2f,
    short* __restrict__ elecb, short* __restrict__ hb,
    float* __restrict__ outp)     // d_out: agg scratch in P1/P2, final out in P3
{
    cg::grid_group grid = cg::this_grid();
    __shared__ float part[4][4][256];      // [wave][e][d] (P1 only)

    const int tid  = threadIdx.x;
    const int bid  = blockIdx.x;
    const int idx  = (bid << 8) + tid;     // 0..65535
    const int w    = tid >> 6;
    const int lane = tid & 63;
    const int g    = lane >> 4;
    const int c    = lane & 15;

    float* __restrict__ agg = outp;        // alias: d_out is agg scratch until P3

    // ---------------- P0: prep ----------------
    {
        { // spin tables -> C-fragment order (f32)
            const int kt = idx >> 12;
            const int dt = (idx >> 8) & 15;
            const int l  = (idx >> 2) & 63;
            const int r  = idx & 3;
            const int row = (kt << 4) + ((l >> 4) << 2) + r;
            const int col = (dt << 4) + (l & 15);
            tab_up[idx] = up[row * DIM + col];
            tab_dn[idx] = dn[row * DIM + col];
        }
        if (idx < 16 * 64 * 8) {           // W_edge B-frag (8192)
            const int dt2 = idx >> 9;
            const int l2  = (idx >> 3) & 63;
            const int b   = idx & 7;
            const int j   = ((l2 >> 4) << 3) + b;
            const int d   = (dt2 << 4) + (l2 & 15);
            wedge_arr[idx] = f2bf(Wedge[j * DIM + d]);
        }
        { // W1/W2 -> B-frag bf16 (65536 each)
            const int b  = idx & 7;
            const int l  = (idx >> 3) & 63;
            const int q  = (idx >> 9) & 7;
            const int nt = idx >> 12;
            const int j  = (q << 5) + ((l >> 4) << 3) + b;
            const int d  = (nt << 4) + (l & 15);
            w1f[idx] = f2bf(W1[j * DIM + d]);
            w2f[idx] = f2bf(W2[j * DIM + d]);
        }
        { // elec -> row-major bf16, 4 elems/thread
            const f32x4 v = *(const f32x4*)(elec + (idx << 2));
            bf16x4 o;
            o[0] = f2bf(v[0]); o[1] = f2bf(v[1]); o[2] = f2bf(v[2]); o[3] = f2bf(v[3]);
            *(bf16x4*)(elecb + (idx << 2)) = o;
        }
    }
    __threadfence();
    grid.sync();

    // ---------------- P1: edge ----------------
    {
        const int base = bid << 2;
        const float* __restrict__ tab = (base < N_UP) ? tab_up : tab_dn;
        const float s1 = *s1p;

        bf16x8 a[4][4];
        #pragma unroll
        for (int e = 0; e < 4; ++e) {
            #pragma unroll
            for (int q = 0; q < 4; ++q) {
                const int kt = (w << 2) + q;
                const float* src = eemb +
                    ((size_t)((base + e) * NNUC + (kt << 4) + c) * EDIM + (g << 3));
                f32x4 lo = *(const f32x4*)(src);
                f32x4 hi = *(const f32x4*)(src + 4);
                union { bf16x8 v; short s[8]; } f;
                f.s[0] = f2bf(lo[0]); f.s[1] = f2bf(lo[1]);
                f.s[2] = f2bf(lo[2]); f.s[3] = f2bf(lo[3]);
                f.s[4] = f2bf(hi[0]); f.s[5] = f2bf(hi[1]);
                f.s[6] = f2bf(hi[2]); f.s[7] = f2bf(hi[3]);
                a[e][q] = f.v;
            }
        }

        const int kt0 = (w << 2);
        bf16x8 bnxt = *(const bf16x8*)(wedge_arr + (lane << 3));           // dt=0
        f32x4 tn0, tn1, tn2, tn3;
        tn0 = *(const f32x4*)(tab + ((((kt0 + 0) << 4) + 0) * 64 + lane) * 4);
        tn1 = *(const f32x4*)(tab + ((((kt0 + 1) << 4) + 0) * 64 + lane) * 4);
        tn2 = *(const f32x4*)(tab + ((((kt0 + 2) << 4) + 0) * 64 + lane) * 4);
        tn3 = *(const f32x4*)(tab + ((((kt0 + 3) << 4) + 0) * 64 + lane) * 4);

        const f32x4 zero4 = {0.f, 0.f, 0.f, 0.f};

        #pragma unroll 1
        for (int dt = 0; dt < 16; ++dt) {
            const bf16x8 bcur = bnxt;
            const f32x4 t0 = tn0, t1 = tn1, t2 = tn2, t3 = tn3;
            if (dt < 15) {
                bnxt = *(const bf16x8*)(wedge_arr + (((dt + 1) << 6) + lane) * 8);
                tn0 = *(const f32x4*)(tab + ((((kt0 + 0) << 4) + dt + 1) * 64 + lane) * 4);
                tn1 = *(const f32x4*)(tab + ((((kt0 + 1) << 4) + dt + 1) * 64 + lane) * 4);
                tn2 = *(const f32x4*)(tab + ((((kt0 + 2) << 4) + dt + 1) * 64 + lane) * 4);
                tn3 = *(const f32x4*)(tab + ((((kt0 + 3) << 4) + dt + 1) * 64 + lane) * 4);
            }
            float p[4] = {0.f, 0.f, 0.f, 0.f};
            #pragma unroll
            for (int e = 0; e < 4; ++e) {
                f32x4 cc;
                cc = __builtin_amdgcn_mfma_f32_16x16x32_bf16(a[e][0], bcur, zero4, 0, 0, 0);
                p[e] += cc[0] * t0[0] + cc[1] * t0[1] + cc[2] * t0[2] + cc[3] * t0[3];
                cc = __builtin_amdgcn_mfma_f32_16x16x32_bf16(a[e][1], bcur, zero4, 0, 0, 0);
                p[e] += cc[0] * t1[0] + cc[1] * t1[1] + cc[2] * t1[2] + cc[3] * t1[3];
                cc = __builtin_amdgcn_mfma_f32_16x16x32_bf16(a[e][2], bcur, zero4, 0, 0, 0);
                p[e] += cc[0] * t2[0] + cc[1] * t2[1] + cc[2] * t2[2] + cc[3] * t2[3];
                cc = __builtin_amdgcn_mfma_f32_16x16x32_bf16(a[e][3], bcur, zero4, 0, 0, 0);
                p[e] += cc[0] * t3[0] + cc[1] * t3[1] + cc[2] * t3[2] + cc[3] * t3[3];
            }
            #pragma unroll
            for (int e = 0; e < 4; ++e) {
                float v = p[e];
                v += __shfl_xor(v, 16, 64);
                v += __shfl_xor(v, 32, 64);
                if (lane < 16) part[w][e][(dt << 4) + lane] = v;
            }
        }
        __syncthreads();

        for (int t = tid; t < 4 * 256; t += 256) {
            const int e = t >> 8;
            const int d = t & 255;
            const float s = part[0][e][d] + part[1][e][d] + part[2][e][d] + part[3][e][d];
            agg[(size_t)(base + e) * DIM + d] = s * s1;
        }
    }
    __threadfence();
    grid.sync();

    // ---------------- P2: gemm1 ----------------
    {
        const int mt = bid >> 2;
        const int nt = ((bid & 3) << 2) + w;

        const short* abase = elecb + (((mt << 4) + c) << 8) + (g << 3);
        const short* bbase = w1f + (nt << 12) + (lane << 3);
        bf16x8 a[8], b[8];
        #pragma unroll
        for (int q = 0; q < 8; ++q) {
            a[q] = *(const bf16x8*)(abase + (q << 5));
            b[q] = *(const bf16x8*)(bbase + (q << 9));
        }
        f32x4 acc = {0.f, 0.f, 0.f, 0.f};
        #pragma unroll
        for (int q = 0; q < 8; ++q)
            acc = __builtin_amdgcn_mfma_f32_16x16x32_bf16(a[q], b[q], acc, 0, 0, 0);

        const int n  = (nt << 4) + c;
        const float bv = b1[n];
        const float s2 = *s2p;
        #pragma unroll
        for (int r = 0; r < 4; ++r) {
            const int m = (mt << 4) + (g << 2) + r;
            const float y = (acc[r] + bv + agg[(m << 8) + n] * norm[m]) * s2;
            const float sig = 1.f / (1.f + __expf(-y));
            hb[(m << 8) + n] = f2bf(GAIN_F * y * sig);
        }
    }
    __threadfence();
    grid.sync();

    // ---------------- P3: gemm2 ----------------
    {
        const int mt = bid >> 2;
        const int nt = ((bid & 3) << 2) + w;

        const short* abase = hb + (((mt << 4) + c) << 8) + (g << 3);
        const short* bbase = w2f + (nt << 12) + (lane << 3);
        bf16x8 a[8], b[8];
        #pragma unroll
        for (int q = 0; q < 8; ++q) {
            a[q] = *(const bf16x8*)(abase + (q << 5));
            b[q] = *(const bf16x8*)(bbase + (q << 9));
        }
        f32x4 acc = {0.f, 0.f, 0.f, 0.f};
        #pragma unroll
        for (int q = 0; q < 8; ++q)
            acc = __builtin_amdgcn_mfma_f32_16x16x32_bf16(a[q], b[q], acc, 0, 0, 0);

        const int n  = (nt << 4) + c;
        const float bv = b2[n];
        #pragma unroll
        for (int r = 0; r < 4; ++r) {
            const int m = (mt << 4) + (g << 2) + r;
            const float z = acc[r] + bv;
            const float sig = 1.f / (1.f + __expf(-z));
            const float o = GAIN_F * z * sig;
            outp[(m << 8) + n] = (elec[(m << 8) + n] + o) * INV_SQRT2_F;
        }
    }
}

// ---------------------------------------------------------------------------
extern "C" void kernel_launch(void* const* d_in, const int* in_sizes, int n_in,
                              void* d_out, int out_size, void* d_ws, size_t ws_size,
                              hipStream_t stream)
{
    const float* elec  = (const float*)d_in[0];
    const float* up    = (const float*)d_in[1];
    const float* dn    = (const float*)d_in[2];
    const float* eemb  = (const float*)d_in[3];
    // d_in[4] = contr: init-time only, unused at runtime
    const float* norm  = (const float*)d_in[5];
    const float* W1    = (const float*)d_in[6];
    const float* b1    = (const float*)d_in[7];
    const float* Wedge = (const float*)d_in[8];
    const float* W2    = (const float*)d_in[9];
    const float* b2    = (const float*)d_in[10];
    const float* s1    = (const float*)d_in[11];
    const float* s2    = (const float*)d_in[12];

    // ws layout: tab_up 65536 f32 | tab_dn 65536 f32 | then shorts:
    //   wedge_arr 8192 | w1f 65536 | w2f 65536 | elecb 262144 | hb 262144
    float* ws     = (float*)d_ws;
    float* tab_up = ws;
    float* tab_dn = ws + 65536;
    short* sbase  = (short*)(ws + 131072);
    short* warr   = sbase;
    short* w1f    = sbase + 8192;
    short* w2f    = sbase + 8192 + 65536;
    short* elecb  = sbase + 8192 + 131072;
    short* hb     = sbase + 8192 + 131072 + 262144;
    float* outp   = (float*)d_out;   // agg scratch in P1/P2, final output in P3

    void* kargs[] = {
        (void*)&elec, (void*)&up, (void*)&dn, (void*)&eemb, (void*)&norm,
        (void*)&W1, (void*)&b1, (void*)&Wedge, (void*)&W2, (void*)&b2,
        (void*)&s1, (void*)&s2,
        (void*)&tab_up, (void*)&tab_dn, (void*)&warr,
        (void*)&w1f, (void*)&w2f, (void*)&elecb, (void*)&hb, (void*)&outp
    };
    hipLaunchCooperativeKernel((void*)fused_kernel, dim3(256), dim3(256),
                               kargs, 0, stream);
}

// Round 5
// 34.429 us; speedup vs baseline: 5.4616x; 5.4616x over previous
//
#include <hip/hip_runtime.h>
#include <hip/hip_bf16.h>

// Sizes fixed by setup_inputs()
#define N_EL   1024
#define N_UP   512
#define NNUC   256
#define DIM    256
#define EDIM   32

#define GAIN_F      1.7872135f          // 1/std(silu(N(0,1))), analytic
#define INV_SQRT2_F 0.7071067811865476f

typedef __attribute__((ext_vector_type(8))) short bf16x8;
typedef __attribute__((ext_vector_type(4))) short bf16x4;
typedef __attribute__((ext_vector_type(4))) float f32x4;

__device__ __forceinline__ short f2bf(float x) {
    union { __hip_bfloat16 h; short s; } u;
    u.h = __float2bfloat16(x);     // compiler pk-fuses pairs (v_cvt_pk_bf16_f32)
    return u.s;
}

// ---------------------------------------------------------------------------
// K0 prep: layout rearrangement + f32->bf16 conversion (same as R2).
// ---------------------------------------------------------------------------
__global__ __launch_bounds__(256) void prep_kernel(
    const float* __restrict__ up, const float* __restrict__ dn,
    const float* __restrict__ wedge,
    const float* __restrict__ w1, const float* __restrict__ w2,
    const float* __restrict__ elec,
    float* __restrict__ tab_up, float* __restrict__ tab_dn,
    short* __restrict__ wedge_arr,
    short* __restrict__ w1f, short* __restrict__ w2f,
    short* __restrict__ elecb)
{
    const int idx = (blockIdx.x << 8) + threadIdx.x;   // 0..65535

    { // spin tables -> C-fragment order (f32)
        const int kt = idx >> 12;
        const int dt = (idx >> 8) & 15;
        const int l  = (idx >> 2) & 63;
        const int r  = idx & 3;
        const int row = (kt << 4) + ((l >> 4) << 2) + r;
        const int col = (dt << 4) + (l & 15);
        tab_up[idx] = up[row * DIM + col];
        tab_dn[idx] = dn[row * DIM + col];
    }
    if (idx < 16 * 64 * 8) {                           // W_edge B-frag (8192)
        const int dt2 = idx >> 9;
        const int l2  = (idx >> 3) & 63;
        const int b   = idx & 7;
        const int j   = ((l2 >> 4) << 3) + b;
        const int d   = (dt2 << 4) + (l2 & 15);
        wedge_arr[idx] = f2bf(wedge[j * DIM + d]);
    }
    { // W1/W2 -> B-frag bf16 (65536 each)
        const int b  = idx & 7;
        const int l  = (idx >> 3) & 63;
        const int q  = (idx >> 9) & 7;
        const int nt = idx >> 12;
        const int j  = (q << 5) + ((l >> 4) << 3) + b;
        const int d  = (nt << 4) + (l & 15);
        w1f[idx] = f2bf(w1[j * DIM + d]);
        w2f[idx] = f2bf(w2[j * DIM + d]);
    }
    { // elec -> row-major bf16, 4 elems/thread
        const f32x4 v = *(const f32x4*)(elec + (idx << 2));
        bf16x4 o;
        o[0] = f2bf(v[0]); o[1] = f2bf(v[1]); o[2] = f2bf(v[2]); o[3] = f2bf(v[3]);
        *(bf16x4*)(elecb + (idx << 2)) = o;
    }
}

// ---------------------------------------------------------------------------
// K1 fused: block = 4 electrons (rows base..base+3), 4 waves, 3 phases,
// __syncthreads-only (no cross-block deps):
//  PE: edge-GEMM * spin-table * k-reduce -> agg in LDS  (R2 edge body)
//  P1: gemm1 over all 16 col-tiles; rows 4..15 of each MFMA tile discarded;
//      epilogue (g==0 lanes) -> h in LDS (bf16)
//  P2: gemm2 (A from LDS h, garbage rows discarded); epilogue + residual -> out
// ---------------------------------------------------------------------------
__global__ __launch_bounds__(256) void fused_kernel(
    const float* __restrict__ eemb,
    const float* __restrict__ tab_up, const float* __restrict__ tab_dn,
    const short* __restrict__ wedge_arr,
    const short* __restrict__ w1f, const short* __restrict__ w2f,
    const short* __restrict__ elecb, const float* __restrict__ elec,
    const float* __restrict__ norm,
    const float* __restrict__ b1, const float* __restrict__ b2,
    const float* __restrict__ s1p, const float* __restrict__ s2p,
    float* __restrict__ outp)
{
    __shared__ float part[4][4][256];   // [wave][e][d]  16 KB
    __shared__ float agg_s[4][256];     //  4 KB
    __shared__ short h_s[4][256];       //  2 KB (bf16)

    const int tid  = threadIdx.x;
    const int bid  = blockIdx.x;
    const int w    = tid >> 6;
    const int lane = tid & 63;
    const int g    = lane >> 4;
    const int c    = lane & 15;
    const int base = bid << 2;          // this block's 4 electron rows

    // ================= PE: edge =================
    {
        const float* __restrict__ tab = (base < N_UP) ? tab_up : tab_dn;

        bf16x8 a[4][4];
        #pragma unroll
        for (int e = 0; e < 4; ++e) {
            #pragma unroll
            for (int q = 0; q < 4; ++q) {
                const int kt = (w << 2) + q;
                const float* src = eemb +
                    ((size_t)((base + e) * NNUC + (kt << 4) + c) * EDIM + (g << 3));
                f32x4 lo = *(const f32x4*)(src);
                f32x4 hi = *(const f32x4*)(src + 4);
                union { bf16x8 v; short s[8]; } f;
                f.s[0] = f2bf(lo[0]); f.s[1] = f2bf(lo[1]);
                f.s[2] = f2bf(lo[2]); f.s[3] = f2bf(lo[3]);
                f.s[4] = f2bf(hi[0]); f.s[5] = f2bf(hi[1]);
                f.s[6] = f2bf(hi[2]); f.s[7] = f2bf(hi[3]);
                a[e][q] = f.v;
            }
        }

        const int kt0 = (w << 2);
        bf16x8 bnxt = *(const bf16x8*)(wedge_arr + (lane << 3));           // dt=0
        f32x4 tn0, tn1, tn2, tn3;
        tn0 = *(const f32x4*)(tab + ((((kt0 + 0) << 4) + 0) * 64 + lane) * 4);
        tn1 = *(const f32x4*)(tab + ((((kt0 + 1) << 4) + 0) * 64 + lane) * 4);
        tn2 = *(const f32x4*)(tab + ((((kt0 + 2) << 4) + 0) * 64 + lane) * 4);
        tn3 = *(const f32x4*)(tab + ((((kt0 + 3) << 4) + 0) * 64 + lane) * 4);

        const f32x4 zero4 = {0.f, 0.f, 0.f, 0.f};

        #pragma unroll 1
        for (int dt = 0; dt < 16; ++dt) {
            const bf16x8 bcur = bnxt;
            const f32x4 t0 = tn0, t1 = tn1, t2 = tn2, t3 = tn3;
            if (dt < 15) {
                bnxt = *(const bf16x8*)(wedge_arr + (((dt + 1) << 6) + lane) * 8);
                tn0 = *(const f32x4*)(tab + ((((kt0 + 0) << 4) + dt + 1) * 64 + lane) * 4);
                tn1 = *(const f32x4*)(tab + ((((kt0 + 1) << 4) + dt + 1) * 64 + lane) * 4);
                tn2 = *(const f32x4*)(tab + ((((kt0 + 2) << 4) + dt + 1) * 64 + lane) * 4);
                tn3 = *(const f32x4*)(tab + ((((kt0 + 3) << 4) + dt + 1) * 64 + lane) * 4);
            }
            float p[4] = {0.f, 0.f, 0.f, 0.f};
            #pragma unroll
            for (int e = 0; e < 4; ++e) {
                f32x4 cc;
                cc = __builtin_amdgcn_mfma_f32_16x16x32_bf16(a[e][0], bcur, zero4, 0, 0, 0);
                p[e] += cc[0] * t0[0] + cc[1] * t0[1] + cc[2] * t0[2] + cc[3] * t0[3];
                cc = __builtin_amdgcn_mfma_f32_16x16x32_bf16(a[e][1], bcur, zero4, 0, 0, 0);
                p[e] += cc[0] * t1[0] + cc[1] * t1[1] + cc[2] * t1[2] + cc[3] * t1[3];
                cc = __builtin_amdgcn_mfma_f32_16x16x32_bf16(a[e][2], bcur, zero4, 0, 0, 0);
                p[e] += cc[0] * t2[0] + cc[1] * t2[1] + cc[2] * t2[2] + cc[3] * t2[3];
                cc = __builtin_amdgcn_mfma_f32_16x16x32_bf16(a[e][3], bcur, zero4, 0, 0, 0);
                p[e] += cc[0] * t3[0] + cc[1] * t3[1] + cc[2] * t3[2] + cc[3] * t3[3];
            }
            #pragma unroll
            for (int e = 0; e < 4; ++e) {
                float v = p[e];
                v += __shfl_xor(v, 16, 64);
                v += __shfl_xor(v, 32, 64);
                if (lane < 16) part[w][e][(dt << 4) + lane] = v;
            }
        }
    }
    __syncthreads();
    {
        const float s1 = *s1p;
        for (int t = tid; t < 4 * 256; t += 256) {
            const int e = t >> 8;
            const int d = t & 255;
            agg_s[e][d] = (part[0][e][d] + part[1][e][d] +
                           part[2][e][d] + part[3][e][d]) * s1;
        }
    }
    __syncthreads();

    // ================= P1: gemm1 =================
    {
        const float s2 = *s2p;
        const int arow = (base + c) & (N_EL - 1);          // rows c>=4 discarded
        const short* abase = elecb + (arow << 8) + (g << 3);

        bf16x8 a[8];
        #pragma unroll
        for (int q = 0; q < 8; ++q) a[q] = *(const bf16x8*)(abase + (q << 5));

        const short* bb0 = w1f + ((w << 2) << 12) + (lane << 3);
        bf16x8 b[8], bn[8];
        #pragma unroll
        for (int q = 0; q < 8; ++q) bn[q] = *(const bf16x8*)(bb0 + (q << 9));

        #pragma unroll
        for (int t = 0; t < 4; ++t) {
            #pragma unroll
            for (int q = 0; q < 8; ++q) b[q] = bn[q];
            if (t < 3) {
                const short* bbn = bb0 + ((t + 1) << 12);
                #pragma unroll
                for (int q = 0; q < 8; ++q) bn[q] = *(const bf16x8*)(bbn + (q << 9));
            }
            f32x4 acc = {0.f, 0.f, 0.f, 0.f};
            #pragma unroll
            for (int q = 0; q < 8; ++q)
                acc = __builtin_amdgcn_mfma_f32_16x16x32_bf16(a[q], b[q], acc, 0, 0, 0);

            if (g == 0) {
                const int nt = (w << 2) + t;
                const int n  = (nt << 4) + c;
                const float bv = b1[n];
                #pragma unroll
                for (int r = 0; r < 4; ++r) {
                    const float y = (acc[r] + bv + agg_s[r][n] * norm[base + r]) * s2;
                    const float sig = 1.f / (1.f + __expf(-y));
                    h_s[r][n] = f2bf(GAIN_F * y * sig);
                }
            }
        }
    }
    __syncthreads();

    // ================= P2: gemm2 =================
    {
        bf16x8 a[8];
        #pragma unroll
        for (int q = 0; q < 8; ++q)                        // rows c>=4 garbage/discarded
            a[q] = *(const bf16x8*)(&h_s[c & 3][(q << 5) + (g << 3)]);  // FIX: + (g<<3)

        const short* bb0 = w2f + ((w << 2) << 12) + (lane << 3);
        bf16x8 b[8], bn[8];
        #pragma unroll
        for (int q = 0; q < 8; ++q) bn[q] = *(const bf16x8*)(bb0 + (q << 9));

        #pragma unroll
        for (int t = 0; t < 4; ++t) {
            #pragma unroll
            for (int q = 0; q < 8; ++q) b[q] = bn[q];
            if (t < 3) {
                const short* bbn = bb0 + ((t + 1) << 12);
                #pragma unroll
                for (int q = 0; q < 8; ++q) bn[q] = *(const bf16x8*)(bbn + (q << 9));
            }
            f32x4 acc = {0.f, 0.f, 0.f, 0.f};
            #pragma unroll
            for (int q = 0; q < 8; ++q)
                acc = __builtin_amdgcn_mfma_f32_16x16x32_bf16(a[q], b[q], acc, 0, 0, 0);

            if (g == 0) {
                const int nt = (w << 2) + t;
                const int n  = (nt << 4) + c;
                const float bv = b2[n];
                #pragma unroll
                for (int r = 0; r < 4; ++r) {
                    const float z = acc[r] + bv;
                    const float sig = 1.f / (1.f + __expf(-z));
                    const float o = GAIN_F * z * sig;
                    const int m = base + r;
                    outp[(m << 8) + n] = (elec[(m << 8) + n] + o) * INV_SQRT2_F;
                }
            }
        }
    }
}

// ---------------------------------------------------------------------------
extern "C" void kernel_launch(void* const* d_in, const int* in_sizes, int n_in,
                              void* d_out, int out_size, void* d_ws, size_t ws_size,
                              hipStream_t stream)
{
    const float* elec  = (const float*)d_in[0];
    const float* up    = (const float*)d_in[1];
    const float* dn    = (const float*)d_in[2];
    const float* eemb  = (const float*)d_in[3];
    // d_in[4] = contr: init-time only, unused at runtime
    const float* norm  = (const float*)d_in[5];
    const float* W1    = (const float*)d_in[6];
    const float* b1    = (const float*)d_in[7];
    const float* Wedge = (const float*)d_in[8];
    const float* W2    = (const float*)d_in[9];
    const float* b2    = (const float*)d_in[10];
    const float* s1    = (const float*)d_in[11];
    const float* s2    = (const float*)d_in[12];

    // ws layout: tab_up 65536 f32 | tab_dn 65536 f32 | then shorts:
    //   wedge_arr 8192 | w1f 65536 | w2f 65536 | elecb 262144
    float* ws     = (float*)d_ws;
    float* tab_up = ws;
    float* tab_dn = ws + 65536;
    short* sbase  = (short*)(ws + 131072);
    short* warr   = sbase;
    short* w1f    = sbase + 8192;
    short* w2f    = sbase + 8192 + 65536;
    short* elecb  = sbase + 8192 + 131072;

    prep_kernel <<<256, 256, 0, stream>>>(up, dn, Wedge, W1, W2, elec,
                                          tab_up, tab_dn, warr, w1f, w2f, elecb);
    fused_kernel<<<256, 256, 0, stream>>>(eemb, tab_up, tab_dn, warr, w1f, w2f,
                                          elecb, elec, norm, b1, b2, s1, s2,
                                          (float*)d_out);
}